// Round 8
// baseline (319.523 us; speedup 1.0000x reference)
//
#include <hip/hip_runtime.h>
#include <hip/hip_bf16.h>

using bf16 = __hip_bfloat16;
typedef __attribute__((ext_vector_type(8))) short short8;
typedef __attribute__((ext_vector_type(4))) short short4v;
typedef __attribute__((ext_vector_type(4))) float floatx4;

#define MFMA16(a, b, c) __builtin_amdgcn_mfma_f32_16x16x32_bf16((a), (b), (c), 0, 0, 0)

constexpr int HID = 1024;
constexpr int NH = 16;
constexpr int HD = 64;
constexpr int NB = 2;
constexpr int SEQL = 4096;
// fold 1/sqrt(64) * log2(e) into Q once => p = exp2(qk) directly
#define QPRE 0.18033688011112042f

__device__ __forceinline__ short f32_to_bf16_bits(float p) {
    bf16 b = __float2bfloat16(p);   // RNE
    short s;
    __builtin_memcpy(&s, &b, sizeof(s));
    return s;
}

__device__ __forceinline__ short8 cvt8(floatx4 a, floatx4 b) {
    short8 r;
#pragma unroll
    for (int i = 0; i < 4; ++i) {
        r[i]     = f32_to_bf16_bits(a[i]);
        r[i + 4] = f32_to_bf16_bits(b[i]);
    }
    return r;
}

// async 16B global->LDS (lds dest is wave-uniform base + lane*16)
__device__ __forceinline__ void gld16(const void* g, void* l) {
    __builtin_amdgcn_global_load_lds(
        (const __attribute__((address_space(1))) void*)g,
        (__attribute__((address_space(3))) void*)l, 16, 0, 0);
}

// f32 -> DENSE bf16 pack: 8 f32 (32B) -> 8 contiguous bf16 (16B).
__global__ __launch_bounds__(256)
void cvt_pack(const float* __restrict__ in, short* __restrict__ out, int n8)
{
    const int i = blockIdx.x * 256 + threadIdx.x;
    if (i < n8) {
        const floatx4 a = ((const floatx4*)in)[2 * i];
        const floatx4 b = ((const floatx4*)in)[2 * i + 1];
        ((short8*)out)[i] = cvt8(a, b);
    }
}

// ---------------------------------------------------------------------------
// Shared epilogue for both GEMM kernels. For fragment (i-row block ROW0,
// j-col COL): MODE1 scatters Q(*QPRE)/K->[B,H,N,D], V->[B,H,D,N] (short4
// packed, keys pi-PERMUTED per 64-block -- see flash notes); MODE0 stores
// f32 to out0.
// ---------------------------------------------------------------------------
template <int MODE>
__device__ __forceinline__ void epi_store(
    const floatx4& a4, int row0, int col, float bv,
    void* __restrict__ out0_, bf16* __restrict__ out1, bf16* __restrict__ out2)
{
    const int part = col >> 10;          // 0=Q 1=K 2=V (tile-uniform)
    const int c = col & (HID - 1);
    const int h = c >> 6;
    const int d = c & 63;
    if (MODE == 1 && part == 2) {
        // V^T: 4 consecutive npos -> one 8B packed store, pi-permuted keys:
        // orig 64t+16n+4q+r -> 64t + 32*(n>>1) + 8q + 4*(n&1) + r.
        const int b = row0 >> 12;
        const int npos0 = row0 & (SEQL - 1);
        const int nn = (npos0 >> 4) & 3;
        const int qq = (npos0 >> 2) & 3;
        const int nposP = (npos0 & ~63) | ((nn >> 1) << 5) | (qq << 3) |
                          ((nn & 1) << 2);
        short4v pk;
#pragma unroll
        for (int r = 0; r < 4; ++r)
            pk[r] = f32_to_bf16_bits(a4[r] + bv);
        *(short4v*)(out2 + ((size_t)(b * NH + h) * HD + d) * SEQL + nposP) = pk;
    } else {
#pragma unroll
        for (int r = 0; r < 4; ++r) {
            const int row = row0 + r;
            const float v = a4[r] + bv;
            if (MODE == 0) {
                ((float*)out0_)[(size_t)row * HID + col] = v;
            } else {
                const int b = row >> 12;
                const int npos = row & (SEQL - 1);
                const size_t bh = (size_t)(b * NH + h);
                if (part == 0)
                    ((bf16*)out0_)[(bh * SEQL + npos) * HD + d] =
                        __float2bfloat16(v * QPRE);
                else
                    out1[(bh * SEQL + npos) * HD + d] = __float2bfloat16(v);
            }
        }
    }
}

// ---------------------------------------------------------------------------
// R8: 256x256-tile 8-wave PHASE-SPLIT GEMM (m201-template port, plain HIP).
// C[M,N] = A[M,1024] @ W[N,1024]^T + bias. Dense bf16 operands.
//
// Why: three rounds showed the 128 2-phase structure is pinned at ~450 TF --
// stage+drain+barrier dominates its K-step and responds to NO pipeline lever
// (T1 null R5, BK=32 bank-broken R6, BK=64-dbuf occupancy-negative R7). The
// catalog regime gate: only the 8-phase structure amortizes the stall
// (m201: 1563 TF @4k vs m97's 912).
//
// Geometry: BM=BN=256, BK=64, 512 thr = 8 waves (2m x 4n), per-wave out
// 128x64 = acc[8][4]. LDS = 2dbuf x (A 32K + B 32K) = 128 KB -> 1 block/CU,
// 2 waves/SIMD (m201's occupancy point). Swizzle: our measured-0-conflict
// octet-XOR (phys octet = logical ^ (row&7)), staging source octet
// pre-swizzled -- carried over verbatim from the 128 kernel.
//
// Per K-tile (4 phases), phase q computes C-quadrant q (4x2 frags x 2 kk =
// 16 MFMA) with 12 ds_read_b128; stage-issue for tile t+1 (buf 1-p) happens
// in phases 0-1 (A, then B; 4 gld16 each). Raw s_barrier pairs keep waves
// phase-locked; setprio(1) wraps the MFMA cluster (T5 -- pays in phase-split
// structures). Buffer gate: s_waitcnt vmcnt(0) before phase 3's closing
// barrier -- all of t+1's loads are >=2 phases (~400cyc) old, so the wait is
// covered; 2 buffers make prefetch distance 1 the only race-free choice.
// ---------------------------------------------------------------------------
template <int MODE>
__global__ __launch_bounds__(512, 2)
void gemm_8p(const char* __restrict__ A_, const char* __restrict__ W,
             const float* __restrict__ bias, void* __restrict__ out0_,
             bf16* __restrict__ out1, bf16* __restrict__ out2, int nx)
{
    __shared__ __align__(16) short As[2][256 * 64];   // 64 KB
    __shared__ __align__(16) short Bs[2][256 * 64];   // 64 KB
    const int tid  = threadIdx.x;
    const int wave = tid >> 6;        // 0..7
    const int lane = tid & 63;
    const int quad = lane >> 4;
    const int l16  = lane & 15;
    const int sw   = l16 & 7;         // read-side swizzle key (row & 7)
    const int wm   = wave >> 2;       // 0..1  (M half)
    const int wn   = wave & 3;        // 0..3  (N quarter)

    // XCD-aware bijective remap (1-D grid, nwg % 8 == 0)
    const int bid  = blockIdx.x;
    const int cpx  = gridDim.x >> 3;
    const int swzb = (bid & 7) * cpx + (bid >> 3);
    const int m0   = (swzb / nx) * 256;
    const int n0   = (swzb % nx) * 256;

    // staging: wave stages rows [wave*32, wave*32+32) of the 256-row tile;
    // 4 gld16 per operand per K-tile (8 rows each). lane -> row lane>>3,
    // source octet (lane&7)^(row&7)  [proven 0-conflict layout].
    const int lr   = lane >> 3;
    const int lcs  = (lane & 7) ^ (lr & 7);
    const char* ag = A_ + ((size_t)(m0 + wave * 32 + lr) * HID + lcs * 8) * 2;
    const char* bg = W  + ((size_t)(n0 + wave * 32 + lr) * HID + lcs * 8) * 2;
    const size_t row8 = (size_t)HID * 8 * 2;   // 8-row stride (bytes)

    floatx4 acc[8][4];
#pragma unroll
    for (int i = 0; i < 8; ++i)
#pragma unroll
        for (int j = 0; j < 4; ++j)
            acc[i][j] = (floatx4){0.f, 0.f, 0.f, 0.f};

    // stage half (u=0: loads 0,1 -> rows +0..15; u=1: loads 2,3 -> rows +16..31)
    auto stageA = [&](int k0, int buf, int u) {
#pragma unroll
        for (int i = 2 * u; i < 2 * u + 2; ++i)
            gld16(ag + (size_t)i * row8 + (size_t)k0 * 2,
                  &As[buf][(wave * 32 + i * 8) * 64]);
    };
    auto stageB = [&](int k0, int buf, int u) {
#pragma unroll
        for (int i = 2 * u; i < 2 * u + 2; ++i)
            gld16(bg + (size_t)i * row8 + (size_t)k0 * 2,
                  &Bs[buf][(wave * 32 + i * 8) * 64]);
    };

    constexpr int KT = HID / 64;      // 16 K-tiles

    // prologue: stage tile 0 into buf 0, drain, sync
    stageA(0, 0, 0); stageA(0, 0, 1);
    stageB(0, 0, 0); stageB(0, 0, 1);
    asm volatile("s_waitcnt vmcnt(0)" ::: "memory");
    __builtin_amdgcn_s_barrier();

    for (int kt = 0; kt < KT; ++kt) {
        const int p    = kt & 1;
        const int kn   = (kt + 1) * 64;
        const bool more = (kt + 1 < KT);
#pragma unroll
        for (int q = 0; q < 4; ++q) {
            const int qi = q >> 1, qj = q & 1;    // C-quadrant (row/col half)
            // ds-read this quadrant's fragments (12 x ds_read_b128)
            short8 af[4][2], bf[2][2];
#pragma unroll
            for (int i4 = 0; i4 < 4; ++i4)
#pragma unroll
                for (int kk = 0; kk < 2; ++kk)
                    af[i4][kk] = *(const short8*)(
                        &As[p][(wm * 128 + (qi * 4 + i4) * 16 + l16) * 64 +
                               (((kk * 4 + quad) ^ sw) * 8)]);
#pragma unroll
            for (int j2 = 0; j2 < 2; ++j2)
#pragma unroll
                for (int kk = 0; kk < 2; ++kk)
                    bf[j2][kk] = *(const short8*)(
                        &Bs[p][(wn * 64 + (qj * 2 + j2) * 16 + l16) * 64 +
                               (((kk * 4 + quad) ^ sw) * 8)]);
            // stage-issue for tile kt+1 into the other buffer (phases 0-1)
            if (more) {
                if (q == 0)      { stageA(kn, 1 - p, 0); stageA(kn, 1 - p, 1); }
                else if (q == 1) { stageB(kn, 1 - p, 0); stageB(kn, 1 - p, 1); }
            }
            __builtin_amdgcn_s_barrier();
            __builtin_amdgcn_s_setprio(1);
#pragma unroll
            for (int i4 = 0; i4 < 4; ++i4)
#pragma unroll
                for (int j2 = 0; j2 < 2; ++j2)
#pragma unroll
                    for (int kk = 0; kk < 2; ++kk)
                        acc[qi * 4 + i4][qj * 2 + j2] =
                            MFMA16(af[i4][kk], bf[j2][kk],
                                   acc[qi * 4 + i4][qj * 2 + j2]);
            __builtin_amdgcn_s_setprio(0);
            if (q == 3) {
                // gate buffer switch: tile kt+1's loads (issued phases 0-1,
                // ~2 phases of MFMA ago) must be landed in ALL waves.
                asm volatile("s_waitcnt vmcnt(0)" ::: "memory");
            }
            __builtin_amdgcn_s_barrier();
            if (q == 3) __builtin_amdgcn_sched_barrier(0);
        }
    }

    // epilogue
#pragma unroll
    for (int j = 0; j < 4; ++j) {
        const int col = n0 + wn * 64 + j * 16 + l16;
        const float bv = bias[col];
#pragma unroll
        for (int i = 0; i < 8; ++i) {
            const int row0 = m0 + wm * 128 + i * 16 + quad * 4;
            epi_store<MODE>(acc[i][j], row0, col, bv, out0_, out1, out2);
        }
    }
}

// ---------------------------------------------------------------------------
// 128-tile single-buffer GEMM (R5 proven form) -- used for gemm2 (MODE0).
// 32 KB LDS -> ~4 blocks/CU; cross-block TLP hides the serial drain (R7
// showed dbuf at lower occupancy loses to this).
// ---------------------------------------------------------------------------
template <int MODE>
__global__ __launch_bounds__(256)
void gemm_bt(const char* __restrict__ A_, const char* __restrict__ W,
             const float* __restrict__ bias, void* __restrict__ out0_,
             bf16* __restrict__ out1, bf16* __restrict__ out2, int nx)
{
    __shared__ __align__(16) short As[128 * 64];
    __shared__ __align__(16) short Bs[128 * 64];
    const int tid  = threadIdx.x;
    const int wave = tid >> 6;
    const int lane = tid & 63;
    const int quad = lane >> 4;
    const int l16  = lane & 15;
    const int sw   = l16 & 7;
    const int wm   = wave >> 1;
    const int wn   = wave & 1;

    const int bid  = blockIdx.x;
    const int cpx  = gridDim.x >> 3;
    const int swzb = (bid & 7) * cpx + (bid >> 3);
    const int m0   = (swzb / nx) * 128;
    const int n0   = (swzb % nx) * 128;

    const int lr   = lane >> 3;
    const int lcs  = (lane & 7) ^ (lr & 7);

    const char* ag = A_ + ((size_t)(m0 + wave * 32 + lr) * HID + lcs * 8) * 2;
    const char* bg = W  + ((size_t)(n0 + wave * 32 + lr) * HID + lcs * 8) * 2;
    const size_t row8 = (size_t)HID * 8 * 2;
    short* asw = As + (wave * 32) * 64;
    short* bsw = Bs + (wave * 32) * 64;

    floatx4 acc[4][4];
#pragma unroll
    for (int i = 0; i < 4; ++i)
#pragma unroll
        for (int j = 0; j < 4; ++j)
            acc[i][j] = (floatx4){0.f, 0.f, 0.f, 0.f};

    for (int k0 = 0; k0 < HID; k0 += 64) {
        __syncthreads();
#pragma unroll
        for (int i = 0; i < 4; ++i) {
            gld16(ag + (size_t)i * row8 + (size_t)k0 * 2, asw + i * 8 * 64);
            gld16(bg + (size_t)i * row8 + (size_t)k0 * 2, bsw + i * 8 * 64);
        }
        __syncthreads();
#pragma unroll
        for (int kk = 0; kk < 2; ++kk) {
            short8 af[4], bfr[4];
#pragma unroll
            for (int i = 0; i < 4; ++i) {
                af[i]  = *(const short8*)(As + (wm * 64 + i * 16 + l16) * 64 +
                                          (((kk * 4 + quad) ^ sw) * 8));
                bfr[i] = *(const short8*)(Bs + (wn * 64 + i * 16 + l16) * 64 +
                                          (((kk * 4 + quad) ^ sw) * 8));
            }
#pragma unroll
            for (int i = 0; i < 4; ++i)
#pragma unroll
                for (int j = 0; j < 4; ++j)
                    acc[i][j] = MFMA16(af[i], bfr[j], acc[i][j]);
        }
    }

#pragma unroll
    for (int j = 0; j < 4; ++j) {
        const int col = n0 + wn * 64 + j * 16 + l16;
        const float bv = bias[col];
#pragma unroll
        for (int i = 0; i < 4; ++i) {
            const int row0 = m0 + wm * 64 + i * 16 + quad * 4;
            epi_store<MODE>(acc[i][j], row0, col, bv, out0_, out1, out2);
        }
    }
}

// ---------------------------------------------------------------------------
// Flash attention (R3 form, unchanged): grid (SEQL/256, B*H), 256 threads
// (4 waves, 64 q-rows each). p = exp2(s), l = ones-MFMA row-sum, O = PV/l.
// s_setprio kept (R4: removing it cost ~10%). QK^T operand-swapped; PV over
// pi-permuted keys; PV A-fragment pure in-register. LDS 32 KB, 2 blocks/CU.
// ---------------------------------------------------------------------------
__global__ __launch_bounds__(256, 2)
void flash_attn(const bf16* __restrict__ Qbf, const bf16* __restrict__ Kbf,
                const bf16* __restrict__ Vtbf, bf16* __restrict__ Og)
{
    __shared__ __align__(16) short Ks[2][64 * 64];  // [buf][key][d], swizzled octets
    __shared__ __align__(16) short Vs[2][64 * 64];  // [buf][d][pi-key], swizzled octets
    const short* Qg = (const short*)Qbf;
    const int tid  = threadIdx.x;
    const int wave = tid >> 6;        // 0..3
    const int lane = tid & 63;
    const int quad = lane >> 4;
    const int l16  = lane & 15;
    const int sw   = l16 & 7;
    const int lr   = lane >> 3;
    const int lcs  = (lane & 7) ^ lr;
    const int bh   = blockIdx.y;
    const int q0   = blockIdx.x * 256;
    const size_t base = (size_t)bh * SEQL * HD;

    short8 qf[4][2];
#pragma unroll
    for (int mt = 0; mt < 4; ++mt) {
        const short* qp = Qg + base + (size_t)(q0 + wave * 64 + mt * 16 + l16) * HD + quad * 8;
        qf[mt][0] = *(const short8*)(qp);
        qf[mt][1] = *(const short8*)(qp + 32);
    }

    const char* kg = (const char*)Kbf + (base + (size_t)(wave * 16 + lr) * HD + lcs * 8) * 2;
    const char* vg = (const char*)Vtbf + (base + (size_t)(wave * 16 + lr) * SEQL + lcs * 8) * 2;

    auto stage = [&](int kt, short* ks, short* vs) {
        const char* k = kg + (size_t)kt * 64 * HD * 2;
        const char* v = vg + (size_t)kt * 64 * 2;
        short* kd = ks + (wave * 16) * 64;
        short* vd = vs + (wave * 16) * 64;
        gld16(k,                      kd);
        gld16(k + (size_t)8 * HD * 2, kd + 8 * 64);
        gld16(v,                        vd);
        gld16(v + (size_t)8 * SEQL * 2, vd + 8 * 64);
    };

    floatx4 oacc[4][4];
    floatx4 lacc[4];
#pragma unroll
    for (int mt = 0; mt < 4; ++mt) {
        lacc[mt] = (floatx4){0.f, 0.f, 0.f, 0.f};
#pragma unroll
        for (int dt = 0; dt < 4; ++dt) oacc[mt][dt] = (floatx4){0.f, 0.f, 0.f, 0.f};
    }

    const short8 ONESF = (short8)(short)0x3F80;

    auto compute = [&](const short* Kb, const short* Vb) {
        short8 kf[2][4];
#pragma unroll
        for (int n = 0; n < 4; ++n) {
            kf[0][n] = *(const short8*)(Kb + (n * 16 + l16) * 64 + ((quad ^ sw) * 8));
            kf[1][n] = *(const short8*)(Kb + (n * 16 + l16) * 64 + (((4 + quad) ^ sw) * 8));
        }
        short8 vf[2][4];
#pragma unroll
        for (int dt = 0; dt < 4; ++dt) {
            vf[0][dt] = *(const short8*)(Vb + (dt * 16 + l16) * 64 + ((quad ^ sw) * 8));
            vf[1][dt] = *(const short8*)(Vb + (dt * 16 + l16) * 64 + (((4 + quad) ^ sw) * 8));
        }

#pragma unroll
        for (int mt = 0; mt < 4; ++mt) {
            floatx4 s[4];
            __builtin_amdgcn_s_setprio(1);
#pragma unroll
            for (int n = 0; n < 4; ++n) {
                s[n] = (floatx4){0.f, 0.f, 0.f, 0.f};
                s[n] = MFMA16(kf[0][n], qf[mt][0], s[n]);
                s[n] = MFMA16(kf[1][n], qf[mt][1], s[n]);
            }
            __builtin_amdgcn_s_setprio(0);
            floatx4 pe[4];
#pragma unroll
            for (int n = 0; n < 4; ++n)
#pragma unroll
                for (int r = 0; r < 4; ++r)
                    pe[n][r] = __builtin_amdgcn_exp2f(s[n][r]);
            const short8 pa0 = cvt8(pe[0], pe[1]);
            const short8 pa1 = cvt8(pe[2], pe[3]);

            __builtin_amdgcn_s_setprio(1);
#pragma unroll
            for (int dt = 0; dt < 4; ++dt) {
                oacc[mt][dt] = MFMA16(pa0, vf[0][dt], oacc[mt][dt]);
                oacc[mt][dt] = MFMA16(pa1, vf[1][dt], oacc[mt][dt]);
            }
            lacc[mt] = MFMA16(pa0, ONESF, lacc[mt]);
            lacc[mt] = MFMA16(pa1, ONESF, lacc[mt]);
            __builtin_amdgcn_s_setprio(0);
        }
    };

    constexpr int NT = SEQL / 64;

    stage(0, Ks[0], Vs[0]);

    for (int kt = 0; kt < NT; kt += 2) {
        __syncthreads();
        if (kt + 1 < NT) stage(kt + 1, Ks[1], Vs[1]);
        compute(Ks[0], Vs[0]);

        __syncthreads();
        if (kt + 2 < NT) stage(kt + 2, Ks[0], Vs[0]);
        if (kt + 1 < NT) compute(Ks[1], Vs[1]);
    }

    const int b = bh >> 4;
    const int h = bh & 15;
#pragma unroll
    for (int mt = 0; mt < 4; ++mt) {
        floatx4 inv;
#pragma unroll
        for (int r = 0; r < 4; ++r) inv[r] = 1.0f / lacc[mt][r];
#pragma unroll
        for (int dt = 0; dt < 4; ++dt) {
#pragma unroll
            for (int r = 0; r < 4; ++r) {
                const int npos = q0 + wave * 64 + mt * 16 + quad * 4 + r;
                const int col = h * HD + dt * 16 + l16;
                Og[((size_t)(b * SEQL + npos)) * HID + col] =
                    __float2bfloat16(oacc[mt][dt][r] * inv[r]);
            }
        }
    }
}

extern "C" void kernel_launch(void* const* d_in, const int* in_sizes, int n_in,
                              void* d_out, int out_size, void* d_ws, size_t ws_size,
                              hipStream_t stream)
{
    const float* x     = (const float*)d_in[0];   // [2,4096,1024] f32
    const float* qkv_w = (const float*)d_in[1];   // [3072,1024]   f32
    const float* qkv_b = (const float*)d_in[2];
    const float* out_w = (const float*)d_in[3];   // [1024,1024]   f32
    const float* out_b = (const float*)d_in[4];
    float* out = (float*)d_out;                   // [2,4096,1024] f32

    const size_t SZ = (size_t)NB * NH * SEQL * HD;  // 8,388,608 elements
    bf16* q_ws  = (bf16*)d_ws;
    bf16* k_ws  = q_ws + SZ;
    bf16* vt_ws = k_ws + SZ;
    bf16* xb    = vt_ws + SZ;         // dense bf16 x -> reused as a_ws
    bf16* a_ws  = xb;
    bf16* wq    = xb + SZ;            // dense bf16 qkv_w -> reused as wo
    bf16* wo    = wq;

    dim3 blk(256);
    cvt_pack<<<dim3((NB * SEQL * HID) / 8 / 256), blk, 0, stream>>>(
        x, (short*)xb, NB * SEQL * HID / 8);
    cvt_pack<<<dim3((3 * HID * HID) / 8 / 256), blk, 0, stream>>>(
        qkv_w, (short*)wq, 3 * HID * HID / 8);

    // gemm1 (8-phase 256^2): nx = 12 n-tiles, ny = 32 m-tiles -> 384 blocks
    {
        const int nx = 3 * HID / 256, ny = NB * SEQL / 256;
        gemm_8p<1><<<dim3(nx * ny), dim3(512), 0, stream>>>(
            (const char*)xb, (const char*)wq, qkv_b, q_ws, k_ws, vt_ws, nx);
    }

    // pack out_w into the (now dead) wq region before flash runs
    cvt_pack<<<dim3((HID * HID) / 8 / 256), blk, 0, stream>>>(
        out_w, (short*)wo, HID * HID / 8);

    flash_attn<<<dim3(SEQL / 256, NB * NH), dim3(256), 0, stream>>>(
        q_ws, k_ws, vt_ws, a_ws);

    // gemm2 (proven 128^2 form): nx = 8 n-tiles, ny = 64 m-tiles -> 512 blocks
    {
        const int nx = HID / 128, ny = NB * SEQL / 128;
        gemm_bt<0><<<dim3(nx * ny), blk, 0, stream>>>(
            (const char*)a_ws, (const char*)wo, out_b, out, nullptr, nullptr, nx);
    }
}